// Round 2
// baseline (41.601 us; speedup 1.0000x reference)
//
#include <hip/hip_runtime.h>

#define NUM_POINTS 2048
#define FEAT 512
#define BATCH 32

using v8s = __attribute__((ext_vector_type(8))) short;
using v4f = __attribute__((ext_vector_type(4))) float;

// fp32 -> bf16 round-to-nearest-even
static __device__ __forceinline__ short f2bf(float x) {
  unsigned u = __float_as_uint(x);
  u += 0x7FFFu + ((u >> 16) & 1u);
  return (short)(u >> 16);
}

static __device__ __forceinline__ v8s cvt8(const float* p) {
  float4 f0 = *(const float4*)(p);
  float4 f1 = *(const float4*)(p + 4);
  v8s r;
  r[0] = f2bf(f0.x); r[1] = f2bf(f0.y); r[2] = f2bf(f0.z); r[3] = f2bf(f0.w);
  r[4] = f2bf(f1.x); r[5] = f2bf(f1.y); r[6] = f2bf(f1.z); r[7] = f2bf(f1.w);
  return r;
}

// One block (256 thr = 4 waves) per position. Split-K: wave w covers
// ks = w*4 .. w*4+3 (K range 128). Partials reduced via LDS, then the
// 32->8->3 tail in fp32.
__global__ void __launch_bounds__(256, 4) fcdec_main(
    const float* __restrict__ glf,
    const float* __restrict__ W1, const float* __restrict__ b1,
    const float* __restrict__ W2, const float* __restrict__ b2,
    const float* __restrict__ W3, const float* __restrict__ b3,
    float* __restrict__ out) {
  __shared__ float red[4][16][64];  // [wave][acc-comp][lane], 16 KB
  __shared__ float h1s[32][33];     // padded, 4.2 KB

  const int t = threadIdx.x;
  const int w = t >> 6;
  const int l = t & 63;
  const int p = blockIdx.x;
  const int lrow = l & 15;
  const int lk = (l >> 4) << 3;  // 0,8,16,24

  v4f acc[2][2] = {};
  const float* A0 = W1 + (size_t)p * 32u * FEAT;

  #pragma unroll
  for (int kk = 0; kk < 4; ++kk) {
    const int ks = w * 4 + kk;
    const int k0 = ks * 32 + lk;
    // A-fragment: lane l holds W1row[row = mt*16 + lrow][k0 .. k0+7]
    v8s a0 = cvt8(A0 + (size_t)(0 * 16 + lrow) * FEAT + k0);
    v8s a1 = cvt8(A0 + (size_t)(1 * 16 + lrow) * FEAT + k0);
    // B-fragment: lane l holds glf[b = nt*16 + lrow][k0 .. k0+7]
    v8s bv0 = cvt8(glf + (size_t)(0 * 16 + lrow) * FEAT + k0);
    v8s bv1 = cvt8(glf + (size_t)(1 * 16 + lrow) * FEAT + k0);
    acc[0][0] = __builtin_amdgcn_mfma_f32_16x16x32_bf16(a0, bv0, acc[0][0], 0, 0, 0);
    acc[0][1] = __builtin_amdgcn_mfma_f32_16x16x32_bf16(a0, bv1, acc[0][1], 0, 0, 0);
    acc[1][0] = __builtin_amdgcn_mfma_f32_16x16x32_bf16(a1, bv0, acc[1][0], 0, 0, 0);
    acc[1][1] = __builtin_amdgcn_mfma_f32_16x16x32_bf16(a1, bv1, acc[1][1], 0, 0, 0);
  }

  // Dump partials: red[w][comp][l], comp = mt*8 + nt*4 + r. Stride-1 in l
  // => conflict-free scalar writes.
  #pragma unroll
  for (int mt = 0; mt < 2; ++mt)
    #pragma unroll
    for (int nt = 0; nt < 2; ++nt)
      #pragma unroll
      for (int r = 0; r < 4; ++r)
        red[w][mt * 8 + nt * 4 + r][l] = acc[mt][nt][r];
  __syncthreads();

  // Reduce across waves: thread t handles lane l = t&63, comps c*4..c*4+3.
  {
    const int c = t >> 6;
    #pragma unroll
    for (int j = 0; j < 4; ++j) {
      const int idx = c * 4 + j;
      float s = red[0][idx][l] + red[1][idx][l] + red[2][idx][l] + red[3][idx][l];
      const int mt = idx >> 3, nt = (idx >> 2) & 1, r = idx & 3;
      const int o = mt * 16 + ((l >> 4) << 2) + r;   // C/D row mapping (m89)
      const int bc = nt * 16 + (l & 15);             // C/D col mapping
      h1s[o][bc] = s + b1[p * 32 + o];
    }
  }
  __syncthreads();

  // Layers 2+3 fp32: one thread per batch.
  if (t < BATCH) {
    const int b = t;
    float h2[8];
    #pragma unroll
    for (int o8 = 0; o8 < 8; ++o8) {
      float s = b2[p * 8 + o8];
      const float* w2 = W2 + (size_t)(p * 8 + o8) * 32;
      #pragma unroll
      for (int i = 0; i < 32; ++i) s += w2[i] * h1s[i][b];
      h2[o8] = s;
    }
    #pragma unroll
    for (int c = 0; c < 3; ++c) {
      float s = b3[p * 3 + c];
      const float* w3 = W3 + (size_t)(p * 3 + c) * 8;
      #pragma unroll
      for (int j = 0; j < 8; ++j) s += w3[j] * h2[j];
      out[(size_t)(b * 3 + c) * NUM_POINTS + p] = s;
    }
  }
}

extern "C" void kernel_launch(void* const* d_in, const int* in_sizes, int n_in,
                              void* d_out, int out_size, void* d_ws, size_t ws_size,
                              hipStream_t stream) {
  const float* glf = (const float*)d_in[0];
  const float* W1  = (const float*)d_in[1];
  const float* b1  = (const float*)d_in[2];
  const float* W2  = (const float*)d_in[3];
  const float* b2  = (const float*)d_in[4];
  const float* W3  = (const float*)d_in[5];
  const float* b3  = (const float*)d_in[6];
  float* out = (float*)d_out;

  hipLaunchKernelGGL(fcdec_main, dim3(NUM_POINTS), dim3(256), 0, stream,
                     glf, W1, b1, W2, b2, W3, b3, out);
}

// Round 3
// 34.307 us; speedup vs baseline: 1.2126x; 1.2126x over previous
//
#include <hip/hip_runtime.h>

#define NUM_POINTS 2048
#define FEAT 512
#define BATCH 32
#define POS_PER_BLOCK 2   // 2 positions x 2 M-split waves = 4 waves/block

using v8s = __attribute__((ext_vector_type(8))) short;
using v4f = __attribute__((ext_vector_type(4))) float;

// fp32 -> bf16 round-to-nearest-even
static __device__ __forceinline__ short f2bf(float x) {
  unsigned u = __float_as_uint(x);
  u += 0x7FFFu + ((u >> 16) & 1u);
  return (short)(u >> 16);
}

static __device__ __forceinline__ v8s cvt8(const float* p) {
  float4 f0 = *(const float4*)(p);
  float4 f1 = *(const float4*)(p + 4);
  v8s r;
  r[0] = f2bf(f0.x); r[1] = f2bf(f0.y); r[2] = f2bf(f0.z); r[3] = f2bf(f0.w);
  r[4] = f2bf(f1.x); r[5] = f2bf(f1.y); r[6] = f2bf(f1.z); r[7] = f2bf(f1.w);
  return r;
}

// Pack glf (fp32 [32][512]) into bf16 MFMA B-fragments in ws (round-1 proven).
// lane l holds B[k = ks*32 + (l>>4)*8 + j][col = nt*16 + (l&15)], j=0..7
// ws index: (((ks*2 + nt)*64 + l)*8 + j)
__global__ void build_bfrag(const float* __restrict__ glf, short* __restrict__ frag) {
  int i = blockIdx.x * 256 + threadIdx.x;  // 0..16383
  int j = i & 7;
  int l = (i >> 3) & 63;
  int nt = (i >> 9) & 1;
  int ks = i >> 10;
  int b = nt * 16 + (l & 15);
  int k = ks * 32 + ((l >> 4) << 3) + j;
  frag[i] = f2bf(glf[b * FEAT + k]);
}

// Split-M: wave w handles position p = blk*2 + (w>>1), output rows mt = w&1.
// Each wave: 16x32 output tile, K=512, reads its own disjoint 16 W1 rows.
__global__ void __launch_bounds__(256) fcdec_main(
    const float* __restrict__ W1, const float* __restrict__ b1,
    const float* __restrict__ W2, const float* __restrict__ b2,
    const float* __restrict__ W3, const float* __restrict__ b3,
    const short* __restrict__ bfrag, float* __restrict__ out) {
  __shared__ float h1s[POS_PER_BLOCK][32][33];  // 8.4 KB

  const int t = threadIdx.x;
  const int w = t >> 6;
  const int l = t & 63;
  const int lp = w >> 1;            // position within block
  const int mt = w & 1;             // M-split
  const int p = blockIdx.x * POS_PER_BLOCK + lp;
  const int lrow = l & 15;
  const int lk = (l >> 4) << 3;     // 0,8,16,24

  v4f acc[2] = {};
  // This wave's 16-row slab of W1
  const float* A0 = W1 + ((size_t)p * 32u + mt * 16 + lrow) * FEAT + lk;

  #pragma unroll 4
  for (int ks = 0; ks < 16; ++ks) {
    v8s a = cvt8(A0 + ks * 32);
    v8s bv0 = *(const v8s*)(bfrag + (((ks * 2 + 0) * 64 + l) << 3));
    v8s bv1 = *(const v8s*)(bfrag + (((ks * 2 + 1) * 64 + l) << 3));
    acc[0] = __builtin_amdgcn_mfma_f32_16x16x32_bf16(a, bv0, acc[0], 0, 0, 0);
    acc[1] = __builtin_amdgcn_mfma_f32_16x16x32_bf16(a, bv1, acc[1], 0, 0, 0);
  }

  // Epilogue: h1 = acc + b1 -> LDS. C/D: lane l holds C[row=(l>>4)*4+r][col=l&15]
  #pragma unroll
  for (int nt = 0; nt < 2; ++nt)
    #pragma unroll
    for (int r = 0; r < 4; ++r) {
      int o = mt * 16 + ((l >> 4) << 2) + r;
      int b = nt * 16 + (l & 15);
      h1s[lp][o][b] = acc[nt][r] + b1[p * 32 + o];
    }
  __syncthreads();

  // Layers 2+3 fp32: one thread per (position-in-block, batch)
  if (t < POS_PER_BLOCK * BATCH) {
    const int tp = t >> 5;
    const int b = t & 31;
    const int pg = blockIdx.x * POS_PER_BLOCK + tp;
    float h2[8];
    #pragma unroll
    for (int o8 = 0; o8 < 8; ++o8) {
      float s = b2[pg * 8 + o8];
      const float* w2 = W2 + (size_t)(pg * 8 + o8) * 32;
      #pragma unroll
      for (int i = 0; i < 32; ++i) s += w2[i] * h1s[tp][i][b];
      h2[o8] = s;
    }
    #pragma unroll
    for (int c = 0; c < 3; ++c) {
      float s = b3[pg * 3 + c];
      const float* w3 = W3 + (size_t)(pg * 3 + c) * 8;
      #pragma unroll
      for (int j = 0; j < 8; ++j) s += w3[j] * h2[j];
      out[(size_t)(b * 3 + c) * NUM_POINTS + pg] = s;
    }
  }
}

extern "C" void kernel_launch(void* const* d_in, const int* in_sizes, int n_in,
                              void* d_out, int out_size, void* d_ws, size_t ws_size,
                              hipStream_t stream) {
  const float* glf = (const float*)d_in[0];
  const float* W1  = (const float*)d_in[1];
  const float* b1  = (const float*)d_in[2];
  const float* W2  = (const float*)d_in[3];
  const float* b2  = (const float*)d_in[4];
  const float* W3  = (const float*)d_in[5];
  const float* b3  = (const float*)d_in[6];
  float* out = (float*)d_out;
  short* frag = (short*)d_ws;  // 32 KB of bf16 B-fragments

  hipLaunchKernelGGL(build_bfrag, dim3(64), dim3(256), 0, stream, glf, frag);
  hipLaunchKernelGGL(fcdec_main, dim3(NUM_POINTS / POS_PER_BLOCK), dim3(256), 0, stream,
                     W1, b1, W2, b2, W3, b3, frag, out);
}